// Round 1
// baseline (464.260 us; speedup 1.0000x reference)
//
#include <hip/hip_runtime.h>

// GCN3: y,h1,h2 = 3-layer GCN. N=50000, E=800000, dims 128->256->128->1.
// Strategy: CSR-by-dst build per call (no fp32 atomics), aggregate at the
// narrow side of each layer (A(xW) == (Ax)W), fp32 everywhere (round 1).

static __device__ __forceinline__ float2 f2fma(float w, float2 u, float2 a){
  a.x = fmaf(w, u.x, a.x); a.y = fmaf(w, u.y, a.y); return a;
}

__global__ void k_count(const int* __restrict__ dst, int* __restrict__ cnt, int E){
  int e = blockIdx.x*256 + threadIdx.x;
  if (e < E) atomicAdd(&cnt[dst[e]], 1);
}

// 2-level exclusive scan over N=50000 (196 blocks of 256; top fits one block)
__global__ void k_scan_block(const int* __restrict__ cnt, int* __restrict__ rowptr,
                             int* __restrict__ bsums, int n){
  __shared__ int sh[256];
  int t = threadIdx.x;
  int i = blockIdx.x*256 + t;
  int v = (i < n) ? cnt[i] : 0;
  sh[t] = v; __syncthreads();
  for (int off = 1; off < 256; off <<= 1){
    int x = (t >= off) ? sh[t-off] : 0;
    __syncthreads();
    sh[t] += x;
    __syncthreads();
  }
  if (i < n) rowptr[i] = sh[t] - v;          // block-local exclusive
  if (t == 255) bsums[blockIdx.x] = sh[255]; // block total
}

__global__ void k_scan_top(int* __restrict__ bsums, int nb){
  __shared__ int sh[256];
  int t = threadIdx.x;
  int v = (t < nb) ? bsums[t] : 0;
  sh[t] = v; __syncthreads();
  for (int off = 1; off < 256; off <<= 1){
    int x = (t >= off) ? sh[t-off] : 0;
    __syncthreads();
    sh[t] += x;
    __syncthreads();
  }
  if (t < nb) bsums[t] = sh[t] - v;          // exclusive, in place
}

__global__ void k_finalize(const int* __restrict__ cnt, int* __restrict__ rowptr,
                           const int* __restrict__ bsums, int* __restrict__ cursor,
                           float* __restrict__ dis, int n){
  int i = blockIdx.x*256 + threadIdx.x;
  if (i < n){
    int r = rowptr[i] + bsums[i >> 8];
    rowptr[i] = r; cursor[i] = r;
    dis[i] = rsqrtf((float)(cnt[i] + 1));    // +1 self loop; deg>=1 always
  }
}

__global__ void k_fill(const int* __restrict__ src, const int* __restrict__ dst,
                       int* __restrict__ cursor, int* __restrict__ csr_src, int E){
  int e = blockIdx.x*256 + threadIdx.x;
  if (e < E){
    int d = dst[e];
    int p = atomicAdd(&cursor[d], 1);
    csr_src[p] = src[e];
  }
}

// out[i,:] = dis[i] * ( dis[i]*in[i,:] + sum_{s in nbr(i)} dis[s]*in[s,:] )
// one wave per node, d=128 -> float2 per lane. Optional +bias,relu.
template<bool RELU>
__global__ void k_agg128(const float* __restrict__ in, float* __restrict__ out,
                         const int* __restrict__ rowptr, const int* __restrict__ cnt,
                         const int* __restrict__ csr_src, const float* __restrict__ dis,
                         const float* __restrict__ bias, int n){
  int t = threadIdx.x;
  int lane = t & 63;
  int node = blockIdx.x*4 + (t >> 6);
  if (node >= n) return;
  const float2* inv = (const float2*)in;
  float di = dis[node];
  float2 v = inv[(size_t)node*64 + lane];
  float2 acc = make_float2(di*v.x, di*v.y);
  int start = rowptr[node];
  int m = cnt[node];
  int j = 0;
  for (; j + 3 < m; j += 4){                 // 4-wide for MLP
    int s0 = csr_src[start+j+0];
    int s1 = csr_src[start+j+1];
    int s2 = csr_src[start+j+2];
    int s3 = csr_src[start+j+3];
    float w0 = dis[s0], w1 = dis[s1], w2 = dis[s2], w3 = dis[s3];
    float2 u0 = inv[(size_t)s0*64 + lane];
    float2 u1 = inv[(size_t)s1*64 + lane];
    float2 u2 = inv[(size_t)s2*64 + lane];
    float2 u3 = inv[(size_t)s3*64 + lane];
    acc = f2fma(w0,u0,acc); acc = f2fma(w1,u1,acc);
    acc = f2fma(w2,u2,acc); acc = f2fma(w3,u3,acc);
  }
  for (; j < m; j++){
    int s = csr_src[start+j];
    acc = f2fma(dis[s], inv[(size_t)s*64 + lane], acc);
  }
  acc.x *= di; acc.y *= di;
  if (RELU){
    float2 b = ((const float2*)bias)[lane];
    acc.x = fmaxf(acc.x + b.x, 0.0f);
    acc.y = fmaxf(acc.y + b.y, 0.0f);
  }
  ((float2*)out)[(size_t)node*64 + lane] = acc;
}

// [n,128] @ [128,256] + b, relu. 32 rows/block, 256 thr: tc=t&63 (4 cols), tr=t>>6 (8 rows)
__global__ __launch_bounds__(256) void k_gemm1(const float* __restrict__ A,
    const float* __restrict__ W, const float* __restrict__ bias,
    float* __restrict__ out, int n){
  __shared__ float xs[32*128];
  int t = threadIdx.x;
  int row0 = blockIdx.x*32;
  {
    const float4* Av = (const float4*)A;
    float4* xsv = (float4*)xs;
    #pragma unroll
    for (int i = 0; i < 4; i++){
      int fi = i*256 + t;                    // 0..1023 float4 slots
      int r = fi >> 5;                       // 32 float4 per row
      float4 v = make_float4(0,0,0,0);
      if (row0 + r < n) v = Av[(size_t)(row0+r)*32 + (fi & 31)];
      xsv[fi] = v;
    }
  }
  __syncthreads();
  int tc = t & 63, tr = t >> 6;
  const float4* Wv = (const float4*)W;       // [128][64] float4
  float4 acc[8];
  #pragma unroll
  for (int j = 0; j < 8; j++) acc[j] = make_float4(0,0,0,0);
  for (int k = 0; k < 128; k++){
    float4 w = Wv[k*64 + tc];
    #pragma unroll
    for (int j = 0; j < 8; j++){
      float a = xs[(tr + 4*j)*128 + k];      // broadcast within wave
      acc[j].x = fmaf(a, w.x, acc[j].x);
      acc[j].y = fmaf(a, w.y, acc[j].y);
      acc[j].z = fmaf(a, w.z, acc[j].z);
      acc[j].w = fmaf(a, w.w, acc[j].w);
    }
  }
  float4 b = ((const float4*)bias)[tc];
  #pragma unroll
  for (int j = 0; j < 8; j++){
    int r = row0 + tr + 4*j;
    if (r < n){
      float4 o;
      o.x = fmaxf(acc[j].x + b.x, 0.0f);
      o.y = fmaxf(acc[j].y + b.y, 0.0f);
      o.z = fmaxf(acc[j].z + b.z, 0.0f);
      o.w = fmaxf(acc[j].w + b.w, 0.0f);
      ((float4*)out)[(size_t)r*64 + tc] = o;
    }
  }
}

// [n,256] @ [256,128], no bias/relu (bias applied after aggregation)
__global__ __launch_bounds__(256) void k_gemm2(const float* __restrict__ A,
    const float* __restrict__ W, float* __restrict__ out, int n){
  __shared__ float xs[32*256];
  int t = threadIdx.x;
  int row0 = blockIdx.x*32;
  {
    const float4* Av = (const float4*)A;
    float4* xsv = (float4*)xs;
    #pragma unroll
    for (int i = 0; i < 8; i++){
      int fi = i*256 + t;                    // 0..2047
      int r = fi >> 6;                       // 64 float4 per row
      float4 v = make_float4(0,0,0,0);
      if (row0 + r < n) v = Av[(size_t)(row0+r)*64 + (fi & 63)];
      xsv[fi] = v;
    }
  }
  __syncthreads();
  int tc = t & 31, tr = t >> 5;              // 32 col-groups, 8 row-lanes
  const float4* Wv = (const float4*)W;       // [256][32] float4
  float4 acc[4];
  #pragma unroll
  for (int j = 0; j < 4; j++) acc[j] = make_float4(0,0,0,0);
  for (int k = 0; k < 256; k++){
    float4 w = Wv[k*32 + tc];
    #pragma unroll
    for (int j = 0; j < 4; j++){
      float a = xs[(tr + 8*j)*256 + k];      // 2 addrs/wave -> free 2-way
      acc[j].x = fmaf(a, w.x, acc[j].x);
      acc[j].y = fmaf(a, w.y, acc[j].y);
      acc[j].z = fmaf(a, w.z, acc[j].z);
      acc[j].w = fmaf(a, w.w, acc[j].w);
    }
  }
  #pragma unroll
  for (int j = 0; j < 4; j++){
    int r = row0 + tr + 8*j;
    if (r < n) ((float4*)out)[(size_t)r*32 + tc] = acc[j];
  }
}

// u[i] = dot(h2[i,:], W3[:,0]) ; one wave per node
__global__ void k_dense3(const float* __restrict__ h2, const float* __restrict__ W3,
                         float* __restrict__ u, int n){
  int t = threadIdx.x;
  int lane = t & 63;
  int node = blockIdx.x*4 + (t >> 6);
  if (node >= n) return;
  float p = fmaf(h2[(size_t)node*128 + lane], W3[lane],
                 h2[(size_t)node*128 + 64 + lane] * W3[64 + lane]);
  #pragma unroll
  for (int off = 32; off > 0; off >>= 1) p += __shfl_down(p, off);
  if (lane == 0) u[node] = p;
}

__global__ void k_agg1d(const float* __restrict__ u, float* __restrict__ y,
                        const int* __restrict__ rowptr, const int* __restrict__ cnt,
                        const int* __restrict__ csr_src, const float* __restrict__ dis,
                        const float* __restrict__ b3, int n){
  int i = blockIdx.x*256 + threadIdx.x;
  if (i >= n) return;
  float di = dis[i];
  float acc = di * u[i];
  int s0 = rowptr[i], m = cnt[i];
  for (int j = 0; j < m; j++){
    int s = csr_src[s0+j];
    acc = fmaf(dis[s], u[s], acc);
  }
  y[i] = fmaf(di, acc, b3[0]);
}

extern "C" void kernel_launch(void* const* d_in, const int* in_sizes, int n_in,
                              void* d_out, int out_size, void* d_ws, size_t ws_size,
                              hipStream_t stream){
  const float* x  = (const float*)d_in[0];
  const int*  ei  = (const int*)d_in[1];
  const float* W1 = (const float*)d_in[2];
  const float* b1 = (const float*)d_in[3];
  const float* W2 = (const float*)d_in[4];
  const float* b2 = (const float*)d_in[5];
  const float* W3 = (const float*)d_in[6];
  const float* b3 = (const float*)d_in[7];
  const int N = in_sizes[0] / 128;
  const int E = in_sizes[1] / 2;
  const int* src = ei;        // edge_index[0]
  const int* dst = ei + E;    // edge_index[1]

  char* p = (char*)d_ws;
  auto alloc = [&](size_t bytes)->char*{
    char* r = p; p += (bytes + 255) & ~(size_t)255; return r;
  };
  int*   cnt     = (int*)  alloc((size_t)N*4);
  int*   rowptr  = (int*)  alloc((size_t)N*4);
  int*   cursor  = (int*)  alloc((size_t)N*4);
  int*   bsums   = (int*)  alloc(1024);
  float* dis     = (float*)alloc((size_t)N*4);
  int*   csr_src = (int*)  alloc((size_t)E*4);
  float* xa      = (float*)alloc((size_t)N*128*4);   // agg(x)
  float* t2      = (float*)alloc((size_t)N*128*4);   // h1 @ W2
  float* u       = (float*)alloc((size_t)N*4);       // h2 @ W3

  float* y  = (float*)d_out;                  // [N]
  float* h1 = y + N;                          // [N,256]
  float* h2 = h1 + (size_t)N*256;             // [N,128]

  hipMemsetAsync(cnt, 0, (size_t)N*4, stream);
  int eb = (E + 255)/256;
  int nb = (N + 255)/256;   // 196 <= 256, fits k_scan_top's single block
  k_count     <<<eb, 256, 0, stream>>>(dst, cnt, E);
  k_scan_block<<<nb, 256, 0, stream>>>(cnt, rowptr, bsums, N);
  k_scan_top  <<<1,  256, 0, stream>>>(bsums, nb);
  k_finalize  <<<nb, 256, 0, stream>>>(cnt, rowptr, bsums, cursor, dis, N);
  k_fill      <<<eb, 256, 0, stream>>>(src, dst, cursor, csr_src, E);

  int ab = (N + 3)/4;       // 4 nodes (waves) per 256-thr block
  int gb = (N + 31)/32;
  // L1: xa = A x ; h1 = relu(xa W1 + b1)
  k_agg128<false><<<ab, 256, 0, stream>>>(x, xa, rowptr, cnt, csr_src, dis, nullptr, N);
  k_gemm1        <<<gb, 256, 0, stream>>>(xa, W1, b1, h1, N);
  // L2: t2 = h1 W2 ; h2 = relu(A t2 + b2)
  k_gemm2        <<<gb, 256, 0, stream>>>(h1, W2, t2, N);
  k_agg128<true> <<<ab, 256, 0, stream>>>(t2, h2, rowptr, cnt, csr_src, dis, b2, N);
  // L3: u = h2 W3 ; y = A u + b3
  k_dense3       <<<ab, 256, 0, stream>>>(h2, W3, u, N);
  k_agg1d        <<<nb, 256, 0, stream>>>(u, y, rowptr, cnt, csr_src, dis, b3, N);
}

// Round 2
// 364.571 us; speedup vs baseline: 1.2734x; 1.2734x over previous
//
#include <hip/hip_runtime.h>

// GCN3 round 2: bf16 MFMA GEMMs (frag-major weight packing, fp32 accum),
// agg L1 emits bf16, dense3 fused into agg L2 epilogue. Aggregations fp32.

typedef __attribute__((ext_vector_type(8))) short short8;   // 8 bf16 (4 VGPR)
typedef __attribute__((ext_vector_type(4))) float f32x4;    // MFMA C/D

static __device__ __forceinline__ unsigned short f2bf(float f){
  union { float f; unsigned u; } v; v.f = f;
  unsigned r = v.u + 0x7FFF + ((v.u >> 16) & 1);            // RNE
  return (unsigned short)(r >> 16);
}
static __device__ __forceinline__ float2 f2fma(float w, float2 u, float2 a){
  a.x = fmaf(w, u.x, a.x); a.y = fmaf(w, u.y, a.y); return a;
}

// ---------------- CSR build ----------------
__global__ void k_count(const int* __restrict__ dst, int* __restrict__ cnt, int E){
  int e = blockIdx.x*256 + threadIdx.x;
  if (e < E) atomicAdd(&cnt[dst[e]], 1);
}

__global__ void k_scan_block(const int* __restrict__ cnt, int* __restrict__ rowptr,
                             int* __restrict__ bsums, int n){
  __shared__ int sh[256];
  int t = threadIdx.x;
  int i = blockIdx.x*256 + t;
  int v = (i < n) ? cnt[i] : 0;
  sh[t] = v; __syncthreads();
  for (int off = 1; off < 256; off <<= 1){
    int x = (t >= off) ? sh[t-off] : 0;
    __syncthreads();
    sh[t] += x;
    __syncthreads();
  }
  if (i < n) rowptr[i] = sh[t] - v;
  if (t == 255) bsums[blockIdx.x] = sh[255];
}

__global__ void k_scan_top(int* __restrict__ bsums, int nb){
  __shared__ int sh[256];
  int t = threadIdx.x;
  int v = (t < nb) ? bsums[t] : 0;
  sh[t] = v; __syncthreads();
  for (int off = 1; off < 256; off <<= 1){
    int x = (t >= off) ? sh[t-off] : 0;
    __syncthreads();
    sh[t] += x;
    __syncthreads();
  }
  if (t < nb) bsums[t] = sh[t] - v;
}

__global__ void k_finalize(const int* __restrict__ cnt, int* __restrict__ rowptr,
                           const int* __restrict__ bsums, int* __restrict__ cursor,
                           float* __restrict__ dis, int n){
  int i = blockIdx.x*256 + threadIdx.x;
  if (i < n){
    int r = rowptr[i] + bsums[i >> 8];
    rowptr[i] = r; cursor[i] = r;
    dis[i] = rsqrtf((float)(cnt[i] + 1));
  }
}

__global__ void k_fill(const int* __restrict__ src, const int* __restrict__ dst,
                       int* __restrict__ cursor, int* __restrict__ csr_src, int E){
  int e = blockIdx.x*256 + threadIdx.x;
  if (e < E){
    int d = dst[e];
    int p = atomicAdd(&cursor[d], 1);
    csr_src[p] = src[e];
  }
}

// ---------------- weight packing: frag-major bf16 ----------------
// Wf1 [16 nt][4 kt][64 lane][8 j] from W1[128][256]
// Wf2 [8 kt][8 nt][64 lane][8 j]  from W2[256][128]  (kt outer for K-split staging)
__global__ void k_wprep(const float* __restrict__ W1, const float* __restrict__ W2,
                        unsigned short* __restrict__ Wf1, unsigned short* __restrict__ Wf2){
  int t = blockIdx.x*256 + threadIdx.x;       // 65536 threads
  if (t < 32768){
    int j = t & 7, lane = (t>>3) & 63, kt = (t>>9) & 3, nt = t >> 11;
    int nn = nt*16 + (lane & 15);
    int kk = kt*32 + (lane>>4)*8 + j;
    Wf1[t] = f2bf(W1[kk*256 + nn]);
  } else {
    int o = t - 32768;
    int j = o & 7, lane = (o>>3) & 63, nt = (o>>9) & 7, kt = o >> 12;
    int nn = nt*16 + (lane & 15);
    int kk = kt*32 + (lane>>4)*8 + j;
    Wf2[o] = f2bf(W2[kk*128 + nn]);
  }
}

// ---------------- aggregation L1: x fp32 gather -> xa bf16 ----------------
__global__ void k_aggL1(const float* __restrict__ in, unsigned int* __restrict__ out,
                        const int* __restrict__ rowptr, const int* __restrict__ cnt,
                        const int* __restrict__ csr_src, const float* __restrict__ dis,
                        int n){
  int t = threadIdx.x;
  int lane = t & 63;
  int node = blockIdx.x*4 + (t >> 6);
  if (node >= n) return;
  const float2* inv = (const float2*)in;
  float di = dis[node];
  float2 v = inv[(size_t)node*64 + lane];
  float2 acc = make_float2(di*v.x, di*v.y);
  int start = rowptr[node];
  int mm = cnt[node];
  int j = 0;
  for (; j + 3 < mm; j += 4){
    int s0 = csr_src[start+j+0], s1 = csr_src[start+j+1];
    int s2 = csr_src[start+j+2], s3 = csr_src[start+j+3];
    float w0 = dis[s0], w1 = dis[s1], w2 = dis[s2], w3 = dis[s3];
    float2 u0 = inv[(size_t)s0*64 + lane];
    float2 u1 = inv[(size_t)s1*64 + lane];
    float2 u2 = inv[(size_t)s2*64 + lane];
    float2 u3 = inv[(size_t)s3*64 + lane];
    acc = f2fma(w0,u0,acc); acc = f2fma(w1,u1,acc);
    acc = f2fma(w2,u2,acc); acc = f2fma(w3,u3,acc);
  }
  for (; j < mm; j++){
    int s = csr_src[start+j];
    acc = f2fma(dis[s], inv[(size_t)s*64 + lane], acc);
  }
  acc.x *= di; acc.y *= di;
  out[(size_t)node*64 + lane] =
      (unsigned)f2bf(acc.x) | ((unsigned)f2bf(acc.y) << 16);
}

// ---------------- aggregation L2: t2 fp32 gather -> h2 fp32 (+b2, relu) + u=h2.W3 ----------------
__global__ void k_aggL2(const float* __restrict__ in, float* __restrict__ h2,
                        const int* __restrict__ rowptr, const int* __restrict__ cnt,
                        const int* __restrict__ csr_src, const float* __restrict__ dis,
                        const float* __restrict__ b2, const float* __restrict__ W3,
                        float* __restrict__ u, int n){
  int t = threadIdx.x;
  int lane = t & 63;
  int node = blockIdx.x*4 + (t >> 6);
  if (node >= n) return;
  const float2* inv = (const float2*)in;
  float di = dis[node];
  float2 v = inv[(size_t)node*64 + lane];
  float2 acc = make_float2(di*v.x, di*v.y);
  int start = rowptr[node];
  int mm = cnt[node];
  int j = 0;
  for (; j + 3 < mm; j += 4){
    int s0 = csr_src[start+j+0], s1 = csr_src[start+j+1];
    int s2 = csr_src[start+j+2], s3 = csr_src[start+j+3];
    float w0 = dis[s0], w1 = dis[s1], w2 = dis[s2], w3 = dis[s3];
    float2 u0 = inv[(size_t)s0*64 + lane];
    float2 u1 = inv[(size_t)s1*64 + lane];
    float2 u2 = inv[(size_t)s2*64 + lane];
    float2 u3 = inv[(size_t)s3*64 + lane];
    acc = f2fma(w0,u0,acc); acc = f2fma(w1,u1,acc);
    acc = f2fma(w2,u2,acc); acc = f2fma(w3,u3,acc);
  }
  for (; j < mm; j++){
    int s = csr_src[start+j];
    acc = f2fma(dis[s], inv[(size_t)s*64 + lane], acc);
  }
  float2 b = ((const float2*)b2)[lane];
  acc.x = fmaxf(fmaf(di, acc.x, b.x), 0.0f);
  acc.y = fmaxf(fmaf(di, acc.y, b.y), 0.0f);
  ((float2*)h2)[(size_t)node*64 + lane] = acc;
  // fused dense3: u[node] = dot(h2_row, W3)
  float up = fmaf(acc.x, W3[2*lane], acc.y * W3[2*lane+1]);
  #pragma unroll
  for (int off = 32; off > 0; off >>= 1) up += __shfl_down(up, off);
  if (lane == 0) u[node] = up;
}

// ---------------- GEMM1: xa[n,128]bf16 @ W1[128,256] -> relu(+b1) -> h1 fp32 ----------------
// grid: (n/64 rows) x 2 col-halves. Block: 4 waves, each 16 rows x 128 cols.
__global__ __launch_bounds__(256) void k_gemm1_mfma(
    const unsigned short* __restrict__ Xa, const unsigned short* __restrict__ Wf1,
    const float* __restrict__ bias, float* __restrict__ out, int n)
{
  __shared__ unsigned short Wl[8*4*64*8];   // 32 KB: 8 nt x 4 kt frags
  __shared__ unsigned short As[64*128];     // 16 KB
  int t = threadIdx.x;
  int row0 = (blockIdx.x >> 1) * 64;
  int h = blockIdx.x & 1;
  {
    const float4* src = (const float4*)Wf1 + (size_t)h*2048;
    float4* dst = (float4*)Wl;
    #pragma unroll
    for (int i = 0; i < 8; i++) dst[i*256 + t] = src[i*256 + t];
  }
  {
    const float4* src = (const float4*)Xa;  // 16B = 8 bf16; 16 per row
    float4* dst = (float4*)As;
    #pragma unroll
    for (int i = 0; i < 4; i++){
      int f = i*256 + t, r = f >> 4, c = f & 15;
      float4 v = make_float4(0,0,0,0);
      if (row0 + r < n) v = src[(size_t)(row0+r)*16 + c];
      dst[f] = v;
    }
  }
  __syncthreads();
  int w = t >> 6, lane = t & 63, m = lane & 15, q = lane >> 4;
  int rbase = w*16;
  short8 af[4];
  #pragma unroll
  for (int kt = 0; kt < 4; kt++)
    af[kt] = *(const short8*)&As[(rbase + m)*128 + kt*32 + q*8];
  f32x4 acc[8];
  #pragma unroll
  for (int i = 0; i < 8; i++) acc[i] = (f32x4){0.f,0.f,0.f,0.f};
  #pragma unroll
  for (int nt = 0; nt < 8; nt++){
    #pragma unroll
    for (int kt = 0; kt < 4; kt++){
      short8 bfr = *(const short8*)&Wl[((nt*4 + kt)*64 + lane)*8];
      acc[nt] = __builtin_amdgcn_mfma_f32_16x16x32_bf16(af[kt], bfr, acc[nt], 0, 0, 0);
    }
  }
  int rowa = row0 + rbase + q*4;
  int colb = h*128 + m;
  #pragma unroll
  for (int nt = 0; nt < 8; nt++){
    float b = bias[colb + nt*16];
    #pragma unroll
    for (int r = 0; r < 4; r++){
      int rr = rowa + r;
      if (rr < n) out[(size_t)rr*256 + colb + nt*16] = fmaxf(acc[nt][r] + b, 0.0f);
    }
  }
}

// ---------------- GEMM2: h1[n,256]fp32 @ W2[256,128] -> t2 fp32 (K split in 2) ----------------
__global__ __launch_bounds__(256) void k_gemm2_mfma(
    const float* __restrict__ H1, const unsigned short* __restrict__ Wf2,
    float* __restrict__ T2, int n)
{
  __shared__ unsigned short Wl[4*8*64*8];   // 32 KB: K-half (4 kt) x 8 nt frags
  __shared__ unsigned short As[64*128];     // 16 KB: 64 rows x 128-col K-half, bf16
  int t = threadIdx.x;
  int row0 = blockIdx.x * 64;
  int w = t >> 6, lane = t & 63, m = lane & 15, q = lane >> 4;
  int rbase = w*16;
  f32x4 acc[8];
  #pragma unroll
  for (int i = 0; i < 8; i++) acc[i] = (f32x4){0.f,0.f,0.f,0.f};
  for (int p = 0; p < 2; p++){
    if (p) __syncthreads();                 // drain phase-0 LDS reads before restage
    {
      const float4* src = (const float4*)Wf2 + (size_t)p*2048;
      float4* dst = (float4*)Wl;
      #pragma unroll
      for (int i = 0; i < 8; i++) dst[i*256 + t] = src[i*256 + t];
    }
    {
      #pragma unroll
      for (int i = 0; i < 8; i++){
        int f = i*256 + t;                  // 64 rows x 32 float4 per K-half
        int r = f >> 5, c = f & 31;
        float4 v = make_float4(0,0,0,0);
        if (row0 + r < n) v = ((const float4*)H1)[(size_t)(row0+r)*64 + p*32 + c];
        unsigned lo = (unsigned)f2bf(v.x) | ((unsigned)f2bf(v.y) << 16);
        unsigned hi = (unsigned)f2bf(v.z) | ((unsigned)f2bf(v.w) << 16);
        *(uint2*)&As[(size_t)f*4] = make_uint2(lo, hi);
      }
    }
    __syncthreads();
    short8 af[4];
    #pragma unroll
    for (int kt = 0; kt < 4; kt++)
      af[kt] = *(const short8*)&As[(rbase + m)*128 + kt*32 + q*8];
    #pragma unroll
    for (int nt = 0; nt < 8; nt++){
      #pragma unroll
      for (int kt = 0; kt < 4; kt++){
        short8 bfr = *(const short8*)&Wl[((kt*8 + nt)*64 + lane)*8];
        acc[nt] = __builtin_amdgcn_mfma_f32_16x16x32_bf16(af[kt], bfr, acc[nt], 0, 0, 0);
      }
    }
  }
  int rowa = row0 + rbase + q*4;
  #pragma unroll
  for (int nt = 0; nt < 8; nt++){
    #pragma unroll
    for (int r = 0; r < 4; r++){
      int rr = rowa + r;
      if (rr < n) T2[(size_t)rr*128 + nt*16 + m] = acc[nt][r];
    }
  }
}

// ---------------- final scalar aggregation ----------------
__global__ void k_agg1d(const float* __restrict__ u, float* __restrict__ y,
                        const int* __restrict__ rowptr, const int* __restrict__ cnt,
                        const int* __restrict__ csr_src, const float* __restrict__ dis,
                        const float* __restrict__ b3, int n){
  int i = blockIdx.x*256 + threadIdx.x;
  if (i >= n) return;
  float di = dis[i];
  float acc = di * u[i];
  int s0 = rowptr[i], m = cnt[i];
  for (int j = 0; j < m; j++){
    int s = csr_src[s0+j];
    acc = fmaf(dis[s], u[s], acc);
  }
  y[i] = fmaf(di, acc, b3[0]);
}

extern "C" void kernel_launch(void* const* d_in, const int* in_sizes, int n_in,
                              void* d_out, int out_size, void* d_ws, size_t ws_size,
                              hipStream_t stream){
  const float* x  = (const float*)d_in[0];
  const int*  ei  = (const int*)d_in[1];
  const float* W1 = (const float*)d_in[2];
  const float* b1 = (const float*)d_in[3];
  const float* W2 = (const float*)d_in[4];
  const float* b2 = (const float*)d_in[5];
  const float* W3 = (const float*)d_in[6];
  const float* b3 = (const float*)d_in[7];
  const int N = in_sizes[0] / 128;
  const int E = in_sizes[1] / 2;
  const int* src = ei;
  const int* dst = ei + E;

  char* p = (char*)d_ws;
  auto alloc = [&](size_t bytes)->char*{
    char* r = p; p += (bytes + 255) & ~(size_t)255; return r;
  };
  int*   cnt     = (int*)  alloc((size_t)N*4);
  int*   rowptr  = (int*)  alloc((size_t)N*4);
  int*   cursor  = (int*)  alloc((size_t)N*4);
  int*   bsums   = (int*)  alloc(1024);
  float* dis     = (float*)alloc((size_t)N*4);
  int*   csr_src = (int*)  alloc((size_t)E*4);
  unsigned int*   xa  = (unsigned int*)  alloc((size_t)N*128*2); // bf16 [N][128]
  float* t2      = (float*)alloc((size_t)N*128*4);
  float* u       = (float*)alloc((size_t)N*4);
  unsigned short* wf1 = (unsigned short*)alloc(32768*2);
  unsigned short* wf2 = (unsigned short*)alloc(32768*2);

  float* y  = (float*)d_out;
  float* h1 = y + N;
  float* h2 = h1 + (size_t)N*256;

  hipMemsetAsync(cnt, 0, (size_t)N*4, stream);
  int eb = (E + 255)/256;
  int nb = (N + 255)/256;
  k_count     <<<eb, 256, 0, stream>>>(dst, cnt, E);
  k_scan_block<<<nb, 256, 0, stream>>>(cnt, rowptr, bsums, N);
  k_scan_top  <<<1,  256, 0, stream>>>(bsums, nb);
  k_finalize  <<<nb, 256, 0, stream>>>(cnt, rowptr, bsums, cursor, dis, N);
  k_fill      <<<eb, 256, 0, stream>>>(src, dst, cursor, csr_src, E);
  k_wprep     <<<256, 256, 0, stream>>>(W1, W2, wf1, wf2);

  int ab = (N + 3)/4;
  int rb = (N + 63)/64;
  k_aggL1     <<<ab,   256, 0, stream>>>(x, xa, rowptr, cnt, csr_src, dis, N);
  k_gemm1_mfma<<<rb*2, 256, 0, stream>>>((const unsigned short*)xa, wf1, b1, h1, N);
  k_gemm2_mfma<<<rb,   256, 0, stream>>>(h1, wf2, t2, N);
  k_aggL2     <<<ab,   256, 0, stream>>>(t2, h2, rowptr, cnt, csr_src, dis, b2, W3, u, N);
  k_agg1d     <<<nb,   256, 0, stream>>>(u, y, rowptr, cnt, csr_src, dis, b3, N);
}

// Round 3
// 342.176 us; speedup vs baseline: 1.3568x; 1.0654x over previous
//
#include <hip/hip_runtime.h>

// GCN3 round 3: gathers in bf16 (x pre-converted; t2 emitted bf16 by gemm2),
// fp32 accumulation. bf16 MFMA GEMMs with padded LDS A-tiles. CSR build with
// scan_top merged into finalize.

typedef __attribute__((ext_vector_type(8))) short short8;   // 8 bf16 (4 VGPR)
typedef __attribute__((ext_vector_type(4))) float f32x4;    // MFMA C/D

static __device__ __forceinline__ unsigned short f2bf(float f){
  union { float f; unsigned u; } v; v.f = f;
  unsigned r = v.u + 0x7FFF + ((v.u >> 16) & 1);            // RNE
  return (unsigned short)(r >> 16);
}
static __device__ __forceinline__ float2 bf2f2(unsigned u){
  union { unsigned u; float f; } a, b;
  a.u = u << 16; b.u = u & 0xffff0000u;
  return make_float2(a.f, b.f);
}

// ---------------- CSR build ----------------
__global__ void k_count(const int* __restrict__ dst, int* __restrict__ cnt, int E){
  int e = blockIdx.x*256 + threadIdx.x;
  if (e < E) atomicAdd(&cnt[dst[e]], 1);
}

__global__ void k_scan_block(const int* __restrict__ cnt, int* __restrict__ rowptr,
                             int* __restrict__ bsums, int n){
  __shared__ int sh[256];
  int t = threadIdx.x;
  int i = blockIdx.x*256 + t;
  int v = (i < n) ? cnt[i] : 0;
  sh[t] = v; __syncthreads();
  for (int off = 1; off < 256; off <<= 1){
    int x = (t >= off) ? sh[t-off] : 0;
    __syncthreads();
    sh[t] += x;
    __syncthreads();
  }
  if (i < n) rowptr[i] = sh[t] - v;          // block-local exclusive
  if (t == 255) bsums[blockIdx.x] = sh[255];
}

// finalize with scan_top folded in: every block re-scans bsums (nb<=256) in LDS
__global__ void k_finalize(const int* __restrict__ cnt, int* __restrict__ rowptr,
                           const int* __restrict__ bsums, int* __restrict__ cursor,
                           float* __restrict__ dis, int n, int nb){
  __shared__ int sh[256];
  int t = threadIdx.x;
  int v = (t < nb) ? bsums[t] : 0;
  sh[t] = v; __syncthreads();
  for (int off = 1; off < 256; off <<= 1){
    int x = (t >= off) ? sh[t-off] : 0;
    __syncthreads();
    sh[t] += x;
    __syncthreads();
  }
  int base = (blockIdx.x == 0) ? 0 : sh[blockIdx.x - 1];  // exclusive prefix
  int i = blockIdx.x*256 + t;
  if (i < n){
    int r = rowptr[i] + base;
    rowptr[i] = r; cursor[i] = r;
    dis[i] = rsqrtf((float)(cnt[i] + 1));    // +1 self loop
  }
}

__global__ void k_fill(const int* __restrict__ src, const int* __restrict__ dst,
                       int* __restrict__ cursor, int* __restrict__ csr_src, int E){
  int e = blockIdx.x*256 + threadIdx.x;
  if (e < E){
    int d = dst[e];
    int p = atomicAdd(&cursor[d], 1);
    csr_src[p] = src[e];
  }
}

// ---------------- weight packing: frag-major bf16 ----------------
__global__ void k_wprep(const float* __restrict__ W1, const float* __restrict__ W2,
                        unsigned short* __restrict__ Wf1, unsigned short* __restrict__ Wf2){
  int t = blockIdx.x*256 + threadIdx.x;       // 65536 threads
  if (t < 32768){
    int j = t & 7, lane = (t>>3) & 63, kt = (t>>9) & 3, nt = t >> 11;
    int nn = nt*16 + (lane & 15);
    int kk = kt*32 + (lane>>4)*8 + j;
    Wf1[t] = f2bf(W1[kk*256 + nn]);
  } else {
    int o = t - 32768;
    int j = o & 7, lane = (o>>3) & 63, nt = (o>>9) & 7, kt = o >> 12;
    int nn = nt*16 + (lane & 15);
    int kk = kt*32 + (lane>>4)*8 + j;
    Wf2[o] = f2bf(W2[kk*128 + nn]);
  }
}

// ---------------- x -> bf16 ----------------
__global__ void k_xbf16(const float4* __restrict__ x, uint2* __restrict__ xb, int nv){
  int i = blockIdx.x*256 + threadIdx.x;
  if (i < nv){
    float4 v = x[i];
    xb[i] = make_uint2((unsigned)f2bf(v.x) | ((unsigned)f2bf(v.y) << 16),
                       (unsigned)f2bf(v.z) | ((unsigned)f2bf(v.w) << 16));
  }
}

// ---------------- aggregation L1: bf16 gather -> xa bf16 ----------------
__global__ void k_aggL1(const unsigned* __restrict__ xb, unsigned* __restrict__ out,
                        const int* __restrict__ rowptr, const int* __restrict__ cnt,
                        const int* __restrict__ csr_src, const float* __restrict__ dis,
                        int n){
  int t = threadIdx.x;
  int lane = t & 63;
  int node = blockIdx.x*4 + (t >> 6);
  if (node >= n) return;
  float di = dis[node];
  float2 v = bf2f2(xb[(size_t)node*64 + lane]);
  float2 acc = make_float2(di*v.x, di*v.y);
  int start = rowptr[node];
  int mm = cnt[node];
  int j = 0;
  for (; j + 7 < mm; j += 8){
    int s[8]; unsigned uv[8]; float w[8];
    #pragma unroll
    for (int q = 0; q < 8; q++) s[q] = csr_src[start+j+q];
    #pragma unroll
    for (int q = 0; q < 8; q++){ w[q] = dis[s[q]]; uv[q] = xb[(size_t)s[q]*64 + lane]; }
    #pragma unroll
    for (int q = 0; q < 8; q++){
      float2 u = bf2f2(uv[q]);
      acc.x = fmaf(w[q], u.x, acc.x); acc.y = fmaf(w[q], u.y, acc.y);
    }
  }
  for (; j < mm; j++){
    int s = csr_src[start+j];
    float2 u = bf2f2(xb[(size_t)s*64 + lane]);
    float w = dis[s];
    acc.x = fmaf(w, u.x, acc.x); acc.y = fmaf(w, u.y, acc.y);
  }
  acc.x *= di; acc.y *= di;
  out[(size_t)node*64 + lane] =
      (unsigned)f2bf(acc.x) | ((unsigned)f2bf(acc.y) << 16);
}

// ---------------- aggregation L2: bf16 gather -> h2 fp32 (+b2,relu) + u=h2.W3 ----------------
__global__ void k_aggL2(const unsigned* __restrict__ t2b, float* __restrict__ h2,
                        const int* __restrict__ rowptr, const int* __restrict__ cnt,
                        const int* __restrict__ csr_src, const float* __restrict__ dis,
                        const float* __restrict__ b2, const float* __restrict__ W3,
                        float* __restrict__ u, int n){
  int t = threadIdx.x;
  int lane = t & 63;
  int node = blockIdx.x*4 + (t >> 6);
  if (node >= n) return;
  float di = dis[node];
  float2 v = bf2f2(t2b[(size_t)node*64 + lane]);
  float2 acc = make_float2(di*v.x, di*v.y);
  int start = rowptr[node];
  int mm = cnt[node];
  int j = 0;
  for (; j + 7 < mm; j += 8){
    int s[8]; unsigned uv[8]; float w[8];
    #pragma unroll
    for (int q = 0; q < 8; q++) s[q] = csr_src[start+j+q];
    #pragma unroll
    for (int q = 0; q < 8; q++){ w[q] = dis[s[q]]; uv[q] = t2b[(size_t)s[q]*64 + lane]; }
    #pragma unroll
    for (int q = 0; q < 8; q++){
      float2 uu = bf2f2(uv[q]);
      acc.x = fmaf(w[q], uu.x, acc.x); acc.y = fmaf(w[q], uu.y, acc.y);
    }
  }
  for (; j < mm; j++){
    int s = csr_src[start+j];
    float2 uu = bf2f2(t2b[(size_t)s*64 + lane]);
    float w = dis[s];
    acc.x = fmaf(w, uu.x, acc.x); acc.y = fmaf(w, uu.y, acc.y);
  }
  float2 b = ((const float2*)b2)[lane];
  acc.x = fmaxf(fmaf(di, acc.x, b.x), 0.0f);
  acc.y = fmaxf(fmaf(di, acc.y, b.y), 0.0f);
  ((float2*)h2)[(size_t)node*64 + lane] = acc;
  float up = fmaf(acc.x, W3[2*lane], acc.y * W3[2*lane+1]);
  #pragma unroll
  for (int off = 32; off > 0; off >>= 1) up += __shfl_down(up, off);
  if (lane == 0) u[node] = up;
}

// ---------------- GEMM1: xa[n,128]bf16 @ W1 -> relu(+b1) -> h1 fp32 ----------------
__global__ __launch_bounds__(256) void k_gemm1_mfma(
    const unsigned short* __restrict__ Xa, const unsigned short* __restrict__ Wf1,
    const float* __restrict__ bias, float* __restrict__ out, int n)
{
  __shared__ unsigned short Wl[8*4*64*8];   // 32 KB
  __shared__ unsigned short As[64*136];     // padded: 136*2=272 B row stride
  int t = threadIdx.x;
  int row0 = (blockIdx.x >> 1) * 64;
  int h = blockIdx.x & 1;
  {
    const float4* src = (const float4*)Wf1 + (size_t)h*2048;
    float4* dst = (float4*)Wl;
    #pragma unroll
    for (int i = 0; i < 8; i++) dst[i*256 + t] = src[i*256 + t];
  }
  {
    const float4* src = (const float4*)Xa;  // 16 float4 per 128-col bf16 row
    #pragma unroll
    for (int i = 0; i < 4; i++){
      int f = i*256 + t, r = f >> 4, c = f & 15;
      float4 v = make_float4(0,0,0,0);
      if (row0 + r < n) v = src[(size_t)(row0+r)*16 + c];
      *(float4*)&As[r*136 + c*8] = v;
    }
  }
  __syncthreads();
  int w = t >> 6, lane = t & 63, m = lane & 15, q = lane >> 4;
  int rbase = w*16;
  short8 af[4];
  #pragma unroll
  for (int kt = 0; kt < 4; kt++)
    af[kt] = *(const short8*)&As[(rbase + m)*136 + kt*32 + q*8];
  f32x4 acc[8];
  #pragma unroll
  for (int i = 0; i < 8; i++) acc[i] = (f32x4){0.f,0.f,0.f,0.f};
  #pragma unroll
  for (int nt = 0; nt < 8; nt++){
    #pragma unroll
    for (int kt = 0; kt < 4; kt++){
      short8 bfr = *(const short8*)&Wl[((nt*4 + kt)*64 + lane)*8];
      acc[nt] = __builtin_amdgcn_mfma_f32_16x16x32_bf16(af[kt], bfr, acc[nt], 0, 0, 0);
    }
  }
  int rowa = row0 + rbase + q*4;
  int colb = h*128 + m;
  #pragma unroll
  for (int nt = 0; nt < 8; nt++){
    float b = bias[colb + nt*16];
    #pragma unroll
    for (int r = 0; r < 4; r++){
      int rr = rowa + r;
      if (rr < n) out[(size_t)rr*256 + colb + nt*16] = fmaxf(acc[nt][r] + b, 0.0f);
    }
  }
}

// ---------------- GEMM2: h1[n,256]fp32 @ W2 -> t2 bf16 (K split in 2) ----------------
__global__ __launch_bounds__(256) void k_gemm2_mfma(
    const float* __restrict__ H1, const unsigned short* __restrict__ Wf2,
    unsigned short* __restrict__ T2b, int n)
{
  __shared__ unsigned short Wl[4*8*64*8];   // 32 KB per K-half
  __shared__ unsigned short As[64*136];     // padded bf16 A tile
  int t = threadIdx.x;
  int row0 = blockIdx.x * 64;
  int w = t >> 6, lane = t & 63, m = lane & 15, q = lane >> 4;
  int rbase = w*16;
  f32x4 acc[8];
  #pragma unroll
  for (int i = 0; i < 8; i++) acc[i] = (f32x4){0.f,0.f,0.f,0.f};
  for (int p = 0; p < 2; p++){
    if (p) __syncthreads();
    {
      const float4* src = (const float4*)Wf2 + (size_t)p*2048;
      float4* dst = (float4*)Wl;
      #pragma unroll
      for (int i = 0; i < 8; i++) dst[i*256 + t] = src[i*256 + t];
    }
    {
      #pragma unroll
      for (int i = 0; i < 8; i++){
        int f = i*256 + t;                  // 64 rows x 32 float4 (fp32) per K-half
        int r = f >> 5, c = f & 31;
        float4 v = make_float4(0,0,0,0);
        if (row0 + r < n) v = ((const float4*)H1)[(size_t)(row0+r)*64 + p*32 + c];
        unsigned lo = (unsigned)f2bf(v.x) | ((unsigned)f2bf(v.y) << 16);
        unsigned hi = (unsigned)f2bf(v.z) | ((unsigned)f2bf(v.w) << 16);
        *(uint2*)&As[r*136 + c*4] = make_uint2(lo, hi);
      }
    }
    __syncthreads();
    short8 af[4];
    #pragma unroll
    for (int kt = 0; kt < 4; kt++)
      af[kt] = *(const short8*)&As[(rbase + m)*136 + kt*32 + q*8];
    #pragma unroll
    for (int nt = 0; nt < 8; nt++){
      #pragma unroll
      for (int kt = 0; kt < 4; kt++){
        short8 bfr = *(const short8*)&Wl[((kt*8 + nt)*64 + lane)*8];
        acc[nt] = __builtin_amdgcn_mfma_f32_16x16x32_bf16(af[kt], bfr, acc[nt], 0, 0, 0);
      }
    }
  }
  int rowa = row0 + rbase + q*4;
  #pragma unroll
  for (int nt = 0; nt < 8; nt++){
    #pragma unroll
    for (int r = 0; r < 4; r++){
      int rr = rowa + r;
      if (rr < n) T2b[(size_t)rr*128 + nt*16 + m] = f2bf(acc[nt][r]);
    }
  }
}

// ---------------- final scalar aggregation ----------------
__global__ void k_agg1d(const float* __restrict__ u, float* __restrict__ y,
                        const int* __restrict__ rowptr, const int* __restrict__ cnt,
                        const int* __restrict__ csr_src, const float* __restrict__ dis,
                        const float* __restrict__ b3, int n){
  int i = blockIdx.x*256 + threadIdx.x;
  if (i >= n) return;
  float di = dis[i];
  float acc = di * u[i];
  int s0 = rowptr[i], m = cnt[i];
  for (int j = 0; j < m; j++){
    int s = csr_src[s0+j];
    acc = fmaf(dis[s], u[s], acc);
  }
  y[i] = fmaf(di, acc, b3[0]);
}

extern "C" void kernel_launch(void* const* d_in, const int* in_sizes, int n_in,
                              void* d_out, int out_size, void* d_ws, size_t ws_size,
                              hipStream_t stream){
  const float* x  = (const float*)d_in[0];
  const int*  ei  = (const int*)d_in[1];
  const float* W1 = (const float*)d_in[2];
  const float* b1 = (const float*)d_in[3];
  const float* W2 = (const float*)d_in[4];
  const float* b2 = (const float*)d_in[5];
  const float* W3 = (const float*)d_in[6];
  const float* b3 = (const float*)d_in[7];
  const int N = in_sizes[0] / 128;
  const int E = in_sizes[1] / 2;
  const int* src = ei;
  const int* dst = ei + E;

  char* p = (char*)d_ws;
  auto alloc = [&](size_t bytes)->char*{
    char* r = p; p += (bytes + 255) & ~(size_t)255; return r;
  };
  int*   cnt     = (int*)  alloc((size_t)N*4);
  int*   rowptr  = (int*)  alloc((size_t)N*4);
  int*   cursor  = (int*)  alloc((size_t)N*4);
  int*   bsums   = (int*)  alloc(1024);
  float* dis     = (float*)alloc((size_t)N*4);
  int*   csr_src = (int*)  alloc((size_t)E*4);
  unsigned* xb   = (unsigned*)alloc((size_t)N*128*2);   // bf16 x
  unsigned* xa   = (unsigned*)alloc((size_t)N*128*2);   // bf16 agg(x)
  unsigned short* t2b = (unsigned short*)alloc((size_t)N*128*2); // bf16 h1@W2
  float* u       = (float*)alloc((size_t)N*4);
  unsigned short* wf1 = (unsigned short*)alloc(32768*2);
  unsigned short* wf2 = (unsigned short*)alloc(32768*2);

  float* y  = (float*)d_out;
  float* h1 = y + N;
  float* h2 = h1 + (size_t)N*256;

  hipMemsetAsync(cnt, 0, (size_t)N*4, stream);
  int eb = (E + 255)/256;
  int nb = (N + 255)/256;   // 196 <= 256
  k_count     <<<eb, 256, 0, stream>>>(dst, cnt, E);
  k_scan_block<<<nb, 256, 0, stream>>>(cnt, rowptr, bsums, N);
  k_finalize  <<<nb, 256, 0, stream>>>(cnt, rowptr, bsums, cursor, dis, N, nb);
  k_fill      <<<eb, 256, 0, stream>>>(src, dst, cursor, csr_src, E);
  k_wprep     <<<256, 256, 0, stream>>>(W1, W2, wf1, wf2);
  int xv = N*32;            // float4 count of x
  k_xbf16     <<<(xv+255)/256, 256, 0, stream>>>((const float4*)x, (uint2*)xb, xv);

  int ab = (N + 3)/4;
  int rb = (N + 63)/64;
  k_aggL1     <<<ab,   256, 0, stream>>>(xb, xa, rowptr, cnt, csr_src, dis, N);
  k_gemm1_mfma<<<rb*2, 256, 0, stream>>>((const unsigned short*)xa, wf1, b1, h1, N);
  k_gemm2_mfma<<<rb,   256, 0, stream>>>(h1, wf2, t2b, N);
  k_aggL2     <<<ab,   256, 0, stream>>>((const unsigned*)t2b, h2, rowptr, cnt, csr_src, dis, b2, W3, u, N);
  k_agg1d     <<<nb,   256, 0, stream>>>(u, y, rowptr, cnt, csr_src, dis, b3, N);
}

// Round 4
// 276.648 us; speedup vs baseline: 1.6782x; 1.2369x over previous
//
#include <hip/hip_runtime.h>

// GCN3 round 4: CSR build replaced by bucketed counting sort (k_bin+k_place)
// to kill the 52MB scattered-write amplification of k_fill and the 800K
// global atomics of k_count. csr_src is u16. Aggregations gather bf16.

typedef __attribute__((ext_vector_type(8))) short short8;   // 8 bf16 (4 VGPR)
typedef __attribute__((ext_vector_type(4))) float f32x4;    // MFMA C/D

static __device__ __forceinline__ unsigned short f2bf(float f){
  union { float f; unsigned u; } v; v.f = f;
  unsigned r = v.u + 0x7FFF + ((v.u >> 16) & 1);            // RNE
  return (unsigned short)(r >> 16);
}
static __device__ __forceinline__ float2 bf2f2(unsigned u){
  union { unsigned u; float f; } a, b;
  a.u = u << 16; b.u = u & 0xffff0000u;
  return make_float2(a.f, b.f);
}

// ---------------- CSR build: bucketed counting sort ----------------
// bucket b = dst>>8 (196 buckets for N=50000), fixed capacity 8192 pairs
// (mean 4096, sd ~64 -> 64 sd of headroom). pair = (dst&255)<<16 | src.
__global__ __launch_bounds__(256) void k_bin(
    const int* __restrict__ src, const int* __restrict__ dst,
    int* __restrict__ bcur, unsigned* __restrict__ pairs, int E){
  __shared__ int cl[256];
  int t = threadIdx.x;
  int e0 = blockIdx.x * 4096 + t;
  cl[t] = 0; __syncthreads();
  #pragma unroll
  for (int i = 0; i < 16; i++){
    int e = e0 + i*256;
    if (e < E) atomicAdd(&cl[dst[e] >> 8], 1);
  }
  __syncthreads();
  int c = cl[t];
  int g = (c > 0) ? atomicAdd(&bcur[t], c) : 0;   // reserve contiguous run
  cl[t] = g;                                      // own-slot rw, no race
  __syncthreads();
  #pragma unroll
  for (int i = 0; i < 16; i++){
    int e = e0 + i*256;
    if (e < E){
      int d = dst[e];
      int b = d >> 8;
      int p = atomicAdd(&cl[b], 1);               // LDS cursor
      pairs[(b << 13) + p] = (unsigned)src[e] | ((unsigned)(d & 255) << 16);
    }
  }
}

// one block per bucket: node histogram + scans -> rowptr/cnt/dis + csr scatter
// (scattered u16 writes confined to this bucket's ~8KB csr window)
__global__ __launch_bounds__(256) void k_place(
    const int* __restrict__ bcur, const unsigned* __restrict__ pairs,
    unsigned short* __restrict__ csr_src, int* __restrict__ rowptr,
    int* __restrict__ cnt, float* __restrict__ dis, int n, int nb){
  __shared__ int sh[256];
  __shared__ int ncnt[256];
  int t = threadIdx.x;
  int b = blockIdx.x;
  // exclusive scan of bucket totals -> csr_base for this bucket
  int v = (t < nb) ? bcur[t] : 0;
  sh[t] = v; __syncthreads();
  for (int off = 1; off < 256; off <<= 1){
    int x = (t >= off) ? sh[t-off] : 0;
    __syncthreads(); sh[t] += x; __syncthreads();
  }
  int csr_base = (b == 0) ? 0 : sh[b-1];
  int cnt_b = bcur[b];
  // node-level histogram within bucket
  ncnt[t] = 0; __syncthreads();
  const unsigned* P = pairs + ((size_t)b << 13);
  for (int i = t; i < cnt_b; i += 256) atomicAdd(&ncnt[P[i] >> 16], 1);
  __syncthreads();
  int c = ncnt[t];
  sh[t] = c; __syncthreads();
  for (int off = 1; off < 256; off <<= 1){
    int x = (t >= off) ? sh[t-off] : 0;
    __syncthreads(); sh[t] += x; __syncthreads();
  }
  int noff = sh[t] - c;                           // exclusive within bucket
  int node = (b << 8) + t;
  if (node < n){
    rowptr[node] = csr_base + noff;
    cnt[node] = c;
    dis[node] = rsqrtf((float)(c + 1));           // +1 self loop
  }
  ncnt[t] = noff; __syncthreads();                // reuse as cursors
  for (int i = t; i < cnt_b; i += 256){
    unsigned u = P[i];
    int p = atomicAdd(&ncnt[u >> 16], 1);
    csr_src[csr_base + p] = (unsigned short)(u & 0xffff);
  }
}

// ---------------- weight packing: frag-major bf16 ----------------
__global__ void k_wprep(const float* __restrict__ W1, const float* __restrict__ W2,
                        unsigned short* __restrict__ Wf1, unsigned short* __restrict__ Wf2){
  int t = blockIdx.x*256 + threadIdx.x;       // 65536 threads
  if (t < 32768){
    int j = t & 7, lane = (t>>3) & 63, kt = (t>>9) & 3, nt = t >> 11;
    int nn = nt*16 + (lane & 15);
    int kk = kt*32 + (lane>>4)*8 + j;
    Wf1[t] = f2bf(W1[kk*256 + nn]);
  } else {
    int o = t - 32768;
    int j = o & 7, lane = (o>>3) & 63, nt = (o>>9) & 7, kt = o >> 12;
    int nn = nt*16 + (lane & 15);
    int kk = kt*32 + (lane>>4)*8 + j;
    Wf2[o] = f2bf(W2[kk*128 + nn]);
  }
}

// ---------------- x -> bf16 ----------------
__global__ void k_xbf16(const float4* __restrict__ x, uint2* __restrict__ xb, int nv){
  int i = blockIdx.x*256 + threadIdx.x;
  if (i < nv){
    float4 v = x[i];
    xb[i] = make_uint2((unsigned)f2bf(v.x) | ((unsigned)f2bf(v.y) << 16),
                       (unsigned)f2bf(v.z) | ((unsigned)f2bf(v.w) << 16));
  }
}

// ---------------- aggregation L1: bf16 gather -> xa bf16 ----------------
__global__ void k_aggL1(const unsigned* __restrict__ xb, unsigned* __restrict__ out,
                        const int* __restrict__ rowptr, const int* __restrict__ cnt,
                        const unsigned short* __restrict__ csr_src,
                        const float* __restrict__ dis, int n){
  int t = threadIdx.x;
  int lane = t & 63;
  int node = blockIdx.x*4 + (t >> 6);
  if (node >= n) return;
  float di = dis[node];
  float2 v = bf2f2(xb[(size_t)node*64 + lane]);
  float2 acc = make_float2(di*v.x, di*v.y);
  int start = rowptr[node];
  int mm = cnt[node];
  int j = 0;
  for (; j + 7 < mm; j += 8){
    int s[8]; unsigned uv[8]; float w[8];
    #pragma unroll
    for (int q = 0; q < 8; q++) s[q] = csr_src[start+j+q];
    #pragma unroll
    for (int q = 0; q < 8; q++){ w[q] = dis[s[q]]; uv[q] = xb[(size_t)s[q]*64 + lane]; }
    #pragma unroll
    for (int q = 0; q < 8; q++){
      float2 u = bf2f2(uv[q]);
      acc.x = fmaf(w[q], u.x, acc.x); acc.y = fmaf(w[q], u.y, acc.y);
    }
  }
  for (; j < mm; j++){
    int s = csr_src[start+j];
    float2 u = bf2f2(xb[(size_t)s*64 + lane]);
    float w = dis[s];
    acc.x = fmaf(w, u.x, acc.x); acc.y = fmaf(w, u.y, acc.y);
  }
  acc.x *= di; acc.y *= di;
  out[(size_t)node*64 + lane] =
      (unsigned)f2bf(acc.x) | ((unsigned)f2bf(acc.y) << 16);
}

// ---------------- aggregation L2: bf16 gather -> h2 fp32 (+b2,relu) + u=h2.W3 ----------------
__global__ void k_aggL2(const unsigned* __restrict__ t2b, float* __restrict__ h2,
                        const int* __restrict__ rowptr, const int* __restrict__ cnt,
                        const unsigned short* __restrict__ csr_src,
                        const float* __restrict__ dis,
                        const float* __restrict__ b2, const float* __restrict__ W3,
                        float* __restrict__ u, int n){
  int t = threadIdx.x;
  int lane = t & 63;
  int node = blockIdx.x*4 + (t >> 6);
  if (node >= n) return;
  float di = dis[node];
  float2 v = bf2f2(t2b[(size_t)node*64 + lane]);
  float2 acc = make_float2(di*v.x, di*v.y);
  int start = rowptr[node];
  int mm = cnt[node];
  int j = 0;
  for (; j + 7 < mm; j += 8){
    int s[8]; unsigned uv[8]; float w[8];
    #pragma unroll
    for (int q = 0; q < 8; q++) s[q] = csr_src[start+j+q];
    #pragma unroll
    for (int q = 0; q < 8; q++){ w[q] = dis[s[q]]; uv[q] = t2b[(size_t)s[q]*64 + lane]; }
    #pragma unroll
    for (int q = 0; q < 8; q++){
      float2 uu = bf2f2(uv[q]);
      acc.x = fmaf(w[q], uu.x, acc.x); acc.y = fmaf(w[q], uu.y, acc.y);
    }
  }
  for (; j < mm; j++){
    int s = csr_src[start+j];
    float2 uu = bf2f2(t2b[(size_t)s*64 + lane]);
    float w = dis[s];
    acc.x = fmaf(w, uu.x, acc.x); acc.y = fmaf(w, uu.y, acc.y);
  }
  float2 b = ((const float2*)b2)[lane];
  acc.x = fmaxf(fmaf(di, acc.x, b.x), 0.0f);
  acc.y = fmaxf(fmaf(di, acc.y, b.y), 0.0f);
  ((float2*)h2)[(size_t)node*64 + lane] = acc;
  float up = fmaf(acc.x, W3[2*lane], acc.y * W3[2*lane+1]);
  #pragma unroll
  for (int off = 32; off > 0; off >>= 1) up += __shfl_down(up, off);
  if (lane == 0) u[node] = up;
}

// ---------------- GEMM1: xa[n,128]bf16 @ W1 -> relu(+b1) -> h1 fp32 ----------------
__global__ __launch_bounds__(256) void k_gemm1_mfma(
    const unsigned short* __restrict__ Xa, const unsigned short* __restrict__ Wf1,
    const float* __restrict__ bias, float* __restrict__ out, int n)
{
  __shared__ unsigned short Wl[8*4*64*8];   // 32 KB
  __shared__ unsigned short As[64*136];     // padded row stride
  int t = threadIdx.x;
  int row0 = (blockIdx.x >> 1) * 64;
  int h = blockIdx.x & 1;
  {
    const float4* src = (const float4*)Wf1 + (size_t)h*2048;
    float4* dst = (float4*)Wl;
    #pragma unroll
    for (int i = 0; i < 8; i++) dst[i*256 + t] = src[i*256 + t];
  }
  {
    const float4* src = (const float4*)Xa;
    #pragma unroll
    for (int i = 0; i < 4; i++){
      int f = i*256 + t, r = f >> 4, c = f & 15;
      float4 v = make_float4(0,0,0,0);
      if (row0 + r < n) v = src[(size_t)(row0+r)*16 + c];
      *(float4*)&As[r*136 + c*8] = v;
    }
  }
  __syncthreads();
  int w = t >> 6, lane = t & 63, m = lane & 15, q = lane >> 4;
  int rbase = w*16;
  short8 af[4];
  #pragma unroll
  for (int kt = 0; kt < 4; kt++)
    af[kt] = *(const short8*)&As[(rbase + m)*136 + kt*32 + q*8];
  f32x4 acc[8];
  #pragma unroll
  for (int i = 0; i < 8; i++) acc[i] = (f32x4){0.f,0.f,0.f,0.f};
  #pragma unroll
  for (int nt = 0; nt < 8; nt++){
    #pragma unroll
    for (int kt = 0; kt < 4; kt++){
      short8 bfr = *(const short8*)&Wl[((nt*4 + kt)*64 + lane)*8];
      acc[nt] = __builtin_amdgcn_mfma_f32_16x16x32_bf16(af[kt], bfr, acc[nt], 0, 0, 0);
    }
  }
  int rowa = row0 + rbase + q*4;
  int colb = h*128 + m;
  #pragma unroll
  for (int nt = 0; nt < 8; nt++){
    float b = bias[colb + nt*16];
    #pragma unroll
    for (int r = 0; r < 4; r++){
      int rr = rowa + r;
      if (rr < n) out[(size_t)rr*256 + colb + nt*16] = fmaxf(acc[nt][r] + b, 0.0f);
    }
  }
}

// ---------------- GEMM2: h1[n,256]fp32 @ W2 -> t2 bf16 (K split in 2) ----------------
__global__ __launch_bounds__(256) void k_gemm2_mfma(
    const float* __restrict__ H1, const unsigned short* __restrict__ Wf2,
    unsigned short* __restrict__ T2b, int n)
{
  __shared__ unsigned short Wl[4*8*64*8];   // 32 KB per K-half
  __shared__ unsigned short As[64*136];
  int t = threadIdx.x;
  int row0 = blockIdx.x * 64;
  int w = t >> 6, lane = t & 63, m = lane & 15, q = lane >> 4;
  int rbase = w*16;
  f32x4 acc[8];
  #pragma unroll
  for (int i = 0; i < 8; i++) acc[i] = (f32x4){0.f,0.f,0.f,0.f};
  for (int p = 0; p < 2; p++){
    if (p) __syncthreads();
    {
      const float4* src = (const float4*)Wf2 + (size_t)p*2048;
      float4* dst = (float4*)Wl;
      #pragma unroll
      for (int i = 0; i < 8; i++) dst[i*256 + t] = src[i*256 + t];
    }
    {
      #pragma unroll
      for (int i = 0; i < 8; i++){
        int f = i*256 + t;
        int r = f >> 5, c = f & 31;
        float4 v = make_float4(0,0,0,0);
        if (row0 + r < n) v = ((const float4*)H1)[(size_t)(row0+r)*64 + p*32 + c];
        unsigned lo = (unsigned)f2bf(v.x) | ((unsigned)f2bf(v.y) << 16);
        unsigned hi = (unsigned)f2bf(v.z) | ((unsigned)f2bf(v.w) << 16);
        *(uint2*)&As[r*136 + c*4] = make_uint2(lo, hi);
      }
    }
    __syncthreads();
    short8 af[4];
    #pragma unroll
    for (int kt = 0; kt < 4; kt++)
      af[kt] = *(const short8*)&As[(rbase + m)*136 + kt*32 + q*8];
    #pragma unroll
    for (int nt = 0; nt < 8; nt++){
      #pragma unroll
      for (int kt = 0; kt < 4; kt++){
        short8 bfr = *(const short8*)&Wl[((kt*8 + nt)*64 + lane)*8];
        acc[nt] = __builtin_amdgcn_mfma_f32_16x16x32_bf16(af[kt], bfr, acc[nt], 0, 0, 0);
      }
    }
  }
  int rowa = row0 + rbase + q*4;
  #pragma unroll
  for (int nt = 0; nt < 8; nt++){
    #pragma unroll
    for (int r = 0; r < 4; r++){
      int rr = rowa + r;
      if (rr < n) T2b[(size_t)rr*128 + nt*16 + m] = f2bf(acc[nt][r]);
    }
  }
}

// ---------------- final scalar aggregation ----------------
__global__ void k_agg1d(const float* __restrict__ u, float* __restrict__ y,
                        const int* __restrict__ rowptr, const int* __restrict__ cnt,
                        const unsigned short* __restrict__ csr_src,
                        const float* __restrict__ dis,
                        const float* __restrict__ b3, int n){
  int i = blockIdx.x*256 + threadIdx.x;
  if (i >= n) return;
  float di = dis[i];
  float acc = di * u[i];
  int s0 = rowptr[i], m = cnt[i];
  for (int j = 0; j < m; j++){
    int s = csr_src[s0+j];
    acc = fmaf(dis[s], u[s], acc);
  }
  y[i] = fmaf(di, acc, b3[0]);
}

extern "C" void kernel_launch(void* const* d_in, const int* in_sizes, int n_in,
                              void* d_out, int out_size, void* d_ws, size_t ws_size,
                              hipStream_t stream){
  const float* x  = (const float*)d_in[0];
  const int*  ei  = (const int*)d_in[1];
  const float* W1 = (const float*)d_in[2];
  const float* b1 = (const float*)d_in[3];
  const float* W2 = (const float*)d_in[4];
  const float* b2 = (const float*)d_in[5];
  const float* W3 = (const float*)d_in[6];
  const float* b3 = (const float*)d_in[7];
  const int N = in_sizes[0] / 128;
  const int E = in_sizes[1] / 2;
  const int* src = ei;
  const int* dst = ei + E;
  const int NB = (N + 255) >> 8;      // 196 buckets

  char* p = (char*)d_ws;
  auto alloc = [&](size_t bytes)->char*{
    char* r = p; p += (bytes + 255) & ~(size_t)255; return r;
  };
  int*   bcur    = (int*)  alloc(256*4);
  int*   rowptr  = (int*)  alloc((size_t)N*4);
  int*   cnt     = (int*)  alloc((size_t)N*4);
  float* dis     = (float*)alloc((size_t)N*4);
  unsigned* pairs = (unsigned*)alloc((size_t)NB*8192*4);      // 6.4 MB
  unsigned short* csr_src = (unsigned short*)alloc((size_t)E*2);
  unsigned* xb   = (unsigned*)alloc((size_t)N*128*2);   // bf16 x
  unsigned* xa   = (unsigned*)alloc((size_t)N*128*2);   // bf16 agg(x)
  unsigned short* t2b = (unsigned short*)alloc((size_t)N*128*2);
  float* u       = (float*)alloc((size_t)N*4);
  unsigned short* wf1 = (unsigned short*)alloc(32768*2);
  unsigned short* wf2 = (unsigned short*)alloc(32768*2);

  float* y  = (float*)d_out;
  float* h1 = y + N;
  float* h2 = h1 + (size_t)N*256;

  hipMemsetAsync(bcur, 0, 256*4, stream);
  int bb = (E + 4095)/4096;           // 196
  int nb = (N + 255)/256;
  k_bin   <<<bb, 256, 0, stream>>>(src, dst, bcur, pairs, E);
  k_place <<<NB, 256, 0, stream>>>(bcur, pairs, csr_src, rowptr, cnt, dis, N, NB);
  k_wprep <<<256, 256, 0, stream>>>(W1, W2, wf1, wf2);
  int xv = N*32;
  k_xbf16 <<<(xv+255)/256, 256, 0, stream>>>((const float4*)x, (uint2*)xb, xv);

  int ab = (N + 3)/4;
  int rb = (N + 63)/64;
  k_aggL1     <<<ab,   256, 0, stream>>>(xb, xa, rowptr, cnt, csr_src, dis, N);
  k_gemm1_mfma<<<rb*2, 256, 0, stream>>>((const unsigned short*)xa, wf1, b1, h1, N);
  k_gemm2_mfma<<<rb,   256, 0, stream>>>(h1, wf2, t2b, N);
  k_aggL2     <<<ab,   256, 0, stream>>>((const unsigned*)t2b, h2, rowptr, cnt, csr_src, dis, b2, W3, u, N);
  k_agg1d     <<<nb,   256, 0, stream>>>(u, y, rowptr, cnt, csr_src, dis, b3, N);
}

// Round 5
// 264.012 us; speedup vs baseline: 1.7585x; 1.0479x over previous
//
#include <hip/hip_runtime.h>

// GCN3 round 5: gemm1 emits bf16 shadow h1b (gemm2 stages bf16 directly, no
// fp32 read + convert), wprep+xbf16+bcur-zero fused into k_prep, agg gather
// unroll deepened to 16. CSR build via bucketed counting sort (u16 csr).

typedef __attribute__((ext_vector_type(8))) short short8;   // 8 bf16 (4 VGPR)
typedef __attribute__((ext_vector_type(4))) float f32x4;    // MFMA C/D

static __device__ __forceinline__ unsigned short f2bf(float f){
  union { float f; unsigned u; } v; v.f = f;
  unsigned r = v.u + 0x7FFF + ((v.u >> 16) & 1);            // RNE
  return (unsigned short)(r >> 16);
}
static __device__ __forceinline__ float2 bf2f2(unsigned u){
  union { unsigned u; float f; } a, b;
  a.u = u << 16; b.u = u & 0xffff0000u;
  return make_float2(a.f, b.f);
}

// ---------------- fused prep: W frag-pack + x->bf16 + zero bcur ----------------
__global__ void k_prep(const float* __restrict__ W1, const float* __restrict__ W2,
                       unsigned short* __restrict__ Wf1, unsigned short* __restrict__ Wf2,
                       const float4* __restrict__ x, uint2* __restrict__ xb, int nv,
                       int* __restrict__ bcur){
  int blk = blockIdx.x;
  int tid = threadIdx.x;
  if (blk < 256){
    if (blk == 0) bcur[tid] = 0;
    int t = blk*256 + tid;                    // 65536 weight-pack threads
    if (t < 32768){
      int j = t & 7, lane = (t>>3) & 63, kt = (t>>9) & 3, nt = t >> 11;
      int nn = nt*16 + (lane & 15);
      int kk = kt*32 + (lane>>4)*8 + j;
      Wf1[t] = f2bf(W1[kk*256 + nn]);
    } else {
      int o = t - 32768;
      int j = o & 7, lane = (o>>3) & 63, nt = (o>>9) & 7, kt = o >> 12;
      int nn = nt*16 + (lane & 15);
      int kk = kt*32 + (lane>>4)*8 + j;
      Wf2[o] = f2bf(W2[kk*128 + nn]);
    }
  } else {
    int i = (blk - 256)*256 + tid;
    if (i < nv){
      float4 v = x[i];
      xb[i] = make_uint2((unsigned)f2bf(v.x) | ((unsigned)f2bf(v.y) << 16),
                         (unsigned)f2bf(v.z) | ((unsigned)f2bf(v.w) << 16));
    }
  }
}

// ---------------- CSR build: bucketed counting sort ----------------
// bucket b = dst>>8, capacity 8192 pairs. pair = (dst&255)<<16 | src.
__global__ __launch_bounds__(256) void k_bin(
    const int* __restrict__ src, const int* __restrict__ dst,
    int* __restrict__ bcur, unsigned* __restrict__ pairs, int E){
  __shared__ int cl[256];
  int t = threadIdx.x;
  int e0 = blockIdx.x * 4096 + t;
  cl[t] = 0; __syncthreads();
  #pragma unroll
  for (int i = 0; i < 16; i++){
    int e = e0 + i*256;
    if (e < E) atomicAdd(&cl[dst[e] >> 8], 1);
  }
  __syncthreads();
  int c = cl[t];
  int g = (c > 0) ? atomicAdd(&bcur[t], c) : 0;   // reserve contiguous run
  cl[t] = g;
  __syncthreads();
  #pragma unroll
  for (int i = 0; i < 16; i++){
    int e = e0 + i*256;
    if (e < E){
      int d = dst[e];
      int b = d >> 8;
      int p = atomicAdd(&cl[b], 1);
      pairs[(b << 13) + p] = (unsigned)src[e] | ((unsigned)(d & 255) << 16);
    }
  }
}

__global__ __launch_bounds__(256) void k_place(
    const int* __restrict__ bcur, const unsigned* __restrict__ pairs,
    unsigned short* __restrict__ csr_src, int* __restrict__ rowptr,
    int* __restrict__ cnt, float* __restrict__ dis, int n, int nb){
  __shared__ int sh[256];
  __shared__ int ncnt[256];
  int t = threadIdx.x;
  int b = blockIdx.x;
  int v = (t < nb) ? bcur[t] : 0;
  sh[t] = v; __syncthreads();
  for (int off = 1; off < 256; off <<= 1){
    int x = (t >= off) ? sh[t-off] : 0;
    __syncthreads(); sh[t] += x; __syncthreads();
  }
  int csr_base = (b == 0) ? 0 : sh[b-1];
  int cnt_b = bcur[b];
  ncnt[t] = 0; __syncthreads();
  const unsigned* P = pairs + ((size_t)b << 13);
  for (int i = t; i < cnt_b; i += 256) atomicAdd(&ncnt[P[i] >> 16], 1);
  __syncthreads();
  int c = ncnt[t];
  sh[t] = c; __syncthreads();
  for (int off = 1; off < 256; off <<= 1){
    int x = (t >= off) ? sh[t-off] : 0;
    __syncthreads(); sh[t] += x; __syncthreads();
  }
  int noff = sh[t] - c;
  int node = (b << 8) + t;
  if (node < n){
    rowptr[node] = csr_base + noff;
    cnt[node] = c;
    dis[node] = rsqrtf((float)(c + 1));           // +1 self loop
  }
  ncnt[t] = noff; __syncthreads();
  for (int i = t; i < cnt_b; i += 256){
    unsigned u = P[i];
    int p = atomicAdd(&ncnt[u >> 16], 1);
    csr_src[csr_base + p] = (unsigned short)(u & 0xffff);
  }
}

// ---------------- aggregation L1: bf16 gather -> xa bf16 ----------------
__global__ void k_aggL1(const unsigned* __restrict__ xb, unsigned* __restrict__ out,
                        const int* __restrict__ rowptr, const int* __restrict__ cnt,
                        const unsigned short* __restrict__ csr_src,
                        const float* __restrict__ dis, int n){
  int t = threadIdx.x;
  int lane = t & 63;
  int node = blockIdx.x*4 + (t >> 6);
  if (node >= n) return;
  float di = dis[node];
  float2 v = bf2f2(xb[(size_t)node*64 + lane]);
  float2 acc = make_float2(di*v.x, di*v.y);
  int start = rowptr[node];
  int mm = cnt[node];
  int j = 0;
  for (; j + 15 < mm; j += 16){
    int s[16]; unsigned uv[16]; float w[16];
    #pragma unroll
    for (int q = 0; q < 16; q++) s[q] = csr_src[start+j+q];
    #pragma unroll
    for (int q = 0; q < 16; q++){ w[q] = dis[s[q]]; uv[q] = xb[(size_t)s[q]*64 + lane]; }
    #pragma unroll
    for (int q = 0; q < 16; q++){
      float2 u = bf2f2(uv[q]);
      acc.x = fmaf(w[q], u.x, acc.x); acc.y = fmaf(w[q], u.y, acc.y);
    }
  }
  for (; j + 3 < mm; j += 4){
    int s[4]; unsigned uv[4]; float w[4];
    #pragma unroll
    for (int q = 0; q < 4; q++) s[q] = csr_src[start+j+q];
    #pragma unroll
    for (int q = 0; q < 4; q++){ w[q] = dis[s[q]]; uv[q] = xb[(size_t)s[q]*64 + lane]; }
    #pragma unroll
    for (int q = 0; q < 4; q++){
      float2 u = bf2f2(uv[q]);
      acc.x = fmaf(w[q], u.x, acc.x); acc.y = fmaf(w[q], u.y, acc.y);
    }
  }
  for (; j < mm; j++){
    int s = csr_src[start+j];
    float2 u = bf2f2(xb[(size_t)s*64 + lane]);
    float w = dis[s];
    acc.x = fmaf(w, u.x, acc.x); acc.y = fmaf(w, u.y, acc.y);
  }
  acc.x *= di; acc.y *= di;
  out[(size_t)node*64 + lane] =
      (unsigned)f2bf(acc.x) | ((unsigned)f2bf(acc.y) << 16);
}

// ---------------- aggregation L2: bf16 gather -> h2 fp32 (+b2,relu) + u=h2.W3 ----------------
__global__ void k_aggL2(const unsigned* __restrict__ t2b, float* __restrict__ h2,
                        const int* __restrict__ rowptr, const int* __restrict__ cnt,
                        const unsigned short* __restrict__ csr_src,
                        const float* __restrict__ dis,
                        const float* __restrict__ b2, const float* __restrict__ W3,
                        float* __restrict__ u, int n){
  int t = threadIdx.x;
  int lane = t & 63;
  int node = blockIdx.x*4 + (t >> 6);
  if (node >= n) return;
  float di = dis[node];
  float2 v = bf2f2(t2b[(size_t)node*64 + lane]);
  float2 acc = make_float2(di*v.x, di*v.y);
  int start = rowptr[node];
  int mm = cnt[node];
  int j = 0;
  for (; j + 15 < mm; j += 16){
    int s[16]; unsigned uv[16]; float w[16];
    #pragma unroll
    for (int q = 0; q < 16; q++) s[q] = csr_src[start+j+q];
    #pragma unroll
    for (int q = 0; q < 16; q++){ w[q] = dis[s[q]]; uv[q] = t2b[(size_t)s[q]*64 + lane]; }
    #pragma unroll
    for (int q = 0; q < 16; q++){
      float2 uu = bf2f2(uv[q]);
      acc.x = fmaf(w[q], uu.x, acc.x); acc.y = fmaf(w[q], uu.y, acc.y);
    }
  }
  for (; j + 3 < mm; j += 4){
    int s[4]; unsigned uv[4]; float w[4];
    #pragma unroll
    for (int q = 0; q < 4; q++) s[q] = csr_src[start+j+q];
    #pragma unroll
    for (int q = 0; q < 4; q++){ w[q] = dis[s[q]]; uv[q] = t2b[(size_t)s[q]*64 + lane]; }
    #pragma unroll
    for (int q = 0; q < 4; q++){
      float2 uu = bf2f2(uv[q]);
      acc.x = fmaf(w[q], uu.x, acc.x); acc.y = fmaf(w[q], uu.y, acc.y);
    }
  }
  for (; j < mm; j++){
    int s = csr_src[start+j];
    float2 uu = bf2f2(t2b[(size_t)s*64 + lane]);
    float w = dis[s];
    acc.x = fmaf(w, uu.x, acc.x); acc.y = fmaf(w, uu.y, acc.y);
  }
  float2 b = ((const float2*)b2)[lane];
  acc.x = fmaxf(fmaf(di, acc.x, b.x), 0.0f);
  acc.y = fmaxf(fmaf(di, acc.y, b.y), 0.0f);
  ((float2*)h2)[(size_t)node*64 + lane] = acc;
  float up = fmaf(acc.x, W3[2*lane], acc.y * W3[2*lane+1]);
  #pragma unroll
  for (int off = 32; off > 0; off >>= 1) up += __shfl_down(up, off);
  if (lane == 0) u[node] = up;
}

// ---------------- GEMM1: xa bf16 @ W1 -> h1 fp32 (+b1,relu) + h1b bf16 shadow ----------------
__global__ __launch_bounds__(256) void k_gemm1_mfma(
    const unsigned short* __restrict__ Xa, const unsigned short* __restrict__ Wf1,
    const float* __restrict__ bias, float* __restrict__ out,
    unsigned short* __restrict__ h1b, int n)
{
  __shared__ unsigned short Wl[8*4*64*8];   // 32 KB
  __shared__ unsigned short As[64*136];     // padded row stride
  int t = threadIdx.x;
  int row0 = (blockIdx.x >> 1) * 64;
  int h = blockIdx.x & 1;
  {
    const float4* src = (const float4*)Wf1 + (size_t)h*2048;
    float4* dst = (float4*)Wl;
    #pragma unroll
    for (int i = 0; i < 8; i++) dst[i*256 + t] = src[i*256 + t];
  }
  {
    const float4* src = (const float4*)Xa;
    #pragma unroll
    for (int i = 0; i < 4; i++){
      int f = i*256 + t, r = f >> 4, c = f & 15;
      float4 v = make_float4(0,0,0,0);
      if (row0 + r < n) v = src[(size_t)(row0+r)*16 + c];
      *(float4*)&As[r*136 + c*8] = v;
    }
  }
  __syncthreads();
  int w = t >> 6, lane = t & 63, m = lane & 15, q = lane >> 4;
  int rbase = w*16;
  short8 af[4];
  #pragma unroll
  for (int kt = 0; kt < 4; kt++)
    af[kt] = *(const short8*)&As[(rbase + m)*136 + kt*32 + q*8];
  f32x4 acc[8];
  #pragma unroll
  for (int i = 0; i < 8; i++) acc[i] = (f32x4){0.f,0.f,0.f,0.f};
  #pragma unroll
  for (int nt = 0; nt < 8; nt++){
    #pragma unroll
    for (int kt = 0; kt < 4; kt++){
      short8 bfr = *(const short8*)&Wl[((nt*4 + kt)*64 + lane)*8];
      acc[nt] = __builtin_amdgcn_mfma_f32_16x16x32_bf16(af[kt], bfr, acc[nt], 0, 0, 0);
    }
  }
  int rowa = row0 + rbase + q*4;
  int colb = h*128 + m;
  #pragma unroll
  for (int nt = 0; nt < 8; nt++){
    float b = bias[colb + nt*16];
    #pragma unroll
    for (int r = 0; r < 4; r++){
      int rr = rowa + r;
      if (rr < n){
        float o = fmaxf(acc[nt][r] + b, 0.0f);
        out[(size_t)rr*256 + colb + nt*16] = o;
        h1b[(size_t)rr*256 + colb + nt*16] = f2bf(o);
      }
    }
  }
}

// ---------------- GEMM2: h1b[n,256]bf16 @ W2 -> t2 bf16 (K split in 2) ----------------
__global__ __launch_bounds__(256) void k_gemm2_mfma(
    const unsigned short* __restrict__ H1b, const unsigned short* __restrict__ Wf2,
    unsigned short* __restrict__ T2b, int n)
{
  __shared__ unsigned short Wl[4*8*64*8];   // 32 KB per K-half
  __shared__ unsigned short As[64*136];     // one K-half of A, bf16, padded
  int t = threadIdx.x;
  int row0 = blockIdx.x * 64;
  int w = t >> 6, lane = t & 63, m = lane & 15, q = lane >> 4;
  int rbase = w*16;
  f32x4 acc[8];
  #pragma unroll
  for (int i = 0; i < 8; i++) acc[i] = (f32x4){0.f,0.f,0.f,0.f};
  for (int p = 0; p < 2; p++){
    if (p) __syncthreads();
    {
      const float4* src = (const float4*)Wf2 + (size_t)p*2048;
      float4* dst = (float4*)Wl;
      #pragma unroll
      for (int i = 0; i < 8; i++) dst[i*256 + t] = src[i*256 + t];
    }
    {
      const float4* src = (const float4*)H1b;   // 32 float4 per 256-col row
      #pragma unroll
      for (int i = 0; i < 4; i++){
        int f = i*256 + t, r = f >> 4, c = f & 15;
        float4 v = make_float4(0,0,0,0);
        if (row0 + r < n) v = src[(size_t)(row0+r)*32 + p*16 + c];
        *(float4*)&As[r*136 + c*8] = v;
      }
    }
    __syncthreads();
    short8 af[4];
    #pragma unroll
    for (int kt = 0; kt < 4; kt++)
      af[kt] = *(const short8*)&As[(rbase + m)*136 + kt*32 + q*8];
    #pragma unroll
    for (int nt = 0; nt < 8; nt++){
      #pragma unroll
      for (int kt = 0; kt < 4; kt++){
        short8 bfr = *(const short8*)&Wl[((kt*8 + nt)*64 + lane)*8];
        acc[nt] = __builtin_amdgcn_mfma_f32_16x16x32_bf16(af[kt], bfr, acc[nt], 0, 0, 0);
      }
    }
  }
  int rowa = row0 + rbase + q*4;
  #pragma unroll
  for (int nt = 0; nt < 8; nt++){
    #pragma unroll
    for (int r = 0; r < 4; r++){
      int rr = rowa + r;
      if (rr < n) T2b[(size_t)rr*128 + nt*16 + m] = f2bf(acc[nt][r]);
    }
  }
}

// ---------------- final scalar aggregation ----------------
__global__ void k_agg1d(const float* __restrict__ u, float* __restrict__ y,
                        const int* __restrict__ rowptr, const int* __restrict__ cnt,
                        const unsigned short* __restrict__ csr_src,
                        const float* __restrict__ dis,
                        const float* __restrict__ b3, int n){
  int i = blockIdx.x*256 + threadIdx.x;
  if (i >= n) return;
  float di = dis[i];
  float acc = di * u[i];
  int s0 = rowptr[i], m = cnt[i];
  for (int j = 0; j < m; j++){
    int s = csr_src[s0+j];
    acc = fmaf(dis[s], u[s], acc);
  }
  y[i] = fmaf(di, acc, b3[0]);
}

extern "C" void kernel_launch(void* const* d_in, const int* in_sizes, int n_in,
                              void* d_out, int out_size, void* d_ws, size_t ws_size,
                              hipStream_t stream){
  const float* x  = (const float*)d_in[0];
  const int*  ei  = (const int*)d_in[1];
  const float* W1 = (const float*)d_in[2];
  const float* b1 = (const float*)d_in[3];
  const float* W2 = (const float*)d_in[4];
  const float* b2 = (const float*)d_in[5];
  const float* W3 = (const float*)d_in[6];
  const float* b3 = (const float*)d_in[7];
  const int N = in_sizes[0] / 128;
  const int E = in_sizes[1] / 2;
  const int* src = ei;
  const int* dst = ei + E;
  const int NB = (N + 255) >> 8;      // 196 buckets

  char* p = (char*)d_ws;
  auto alloc = [&](size_t bytes)->char*{
    char* r = p; p += (bytes + 255) & ~(size_t)255; return r;
  };
  int*   bcur    = (int*)  alloc(256*4);
  int*   rowptr  = (int*)  alloc((size_t)N*4);
  int*   cnt     = (int*)  alloc((size_t)N*4);
  float* dis     = (float*)alloc((size_t)N*4);
  unsigned* pairs = (unsigned*)alloc((size_t)NB*8192*4);
  unsigned short* csr_src = (unsigned short*)alloc((size_t)E*2);
  unsigned* xb   = (unsigned*)alloc((size_t)N*128*2);   // bf16 x
  unsigned* xa   = (unsigned*)alloc((size_t)N*128*2);   // bf16 agg(x)
  unsigned short* h1b = (unsigned short*)alloc((size_t)N*256*2); // bf16 h1
  unsigned short* t2b = (unsigned short*)alloc((size_t)N*128*2); // bf16 h1@W2
  float* u       = (float*)alloc((size_t)N*4);
  unsigned short* wf1 = (unsigned short*)alloc(32768*2);
  unsigned short* wf2 = (unsigned short*)alloc(32768*2);

  float* y  = (float*)d_out;
  float* h1 = y + N;
  float* h2 = h1 + (size_t)N*256;

  int bb = (E + 4095)/4096;           // 196
  int nb = (N + 255)/256;
  int xv = N*32;                      // float4 count of x
  k_prep  <<<256 + (xv+255)/256, 256, 0, stream>>>(W1, W2, wf1, wf2,
                                                   (const float4*)x, (uint2*)xb, xv, bcur);
  k_bin   <<<bb, 256, 0, stream>>>(src, dst, bcur, pairs, E);
  k_place <<<NB, 256, 0, stream>>>(bcur, pairs, csr_src, rowptr, cnt, dis, N, NB);

  int ab = (N + 3)/4;
  int rb = (N + 63)/64;
  k_aggL1     <<<ab,   256, 0, stream>>>(xb, xa, rowptr, cnt, csr_src, dis, N);
  k_gemm1_mfma<<<rb*2, 256, 0, stream>>>((const unsigned short*)xa, wf1, b1, h1, h1b, N);
  k_gemm2_mfma<<<rb,   256, 0, stream>>>(h1b, wf2, t2b, N);
  k_aggL2     <<<ab,   256, 0, stream>>>((const unsigned*)t2b, h2, rowptr, cnt, csr_src, dis, b2, W3, u, N);
  k_agg1d     <<<nb,   256, 0, stream>>>(u, y, rowptr, cnt, csr_src, dis, b3, N);
}